// Round 2
// baseline (134.215 us; speedup 1.0000x reference)
//
#include <hip/hip_runtime.h>
#include <math.h>

#define BS 8
#define SEQ 1024
#define DIM 1024
#define FF 4096
#define NE 8
#define TOPK 2
#define NSLOT (BS*TOPK)   // 16 selections (b,j)
#define MAXM 8
#define NCHUNK 64
#define UG_TILE 32        // rows per block in kupgate
#define DN_TILE 16        // rows per block in kdown

// ws layout in floats
#define WS_PARTIAL 0                                  // [BS][NCHUNK][DIM]
#define WS_LOGITS  (WS_PARTIAL + BS*NCHUNK*DIM)
#define WS_SELW    (WS_LOGITS + BS*NE)
#define WS_SELE    (WS_SELW + NSLOT)
#define WS_ACT     (WS_SELE + NSLOT)                  // [NSLOT][FF]
#define WS_Y       (WS_ACT + NSLOT*FF)                // [NSLOT][DIM]

__device__ __forceinline__ float dot4(float4 a, float4 b) {
    return a.x*b.x + a.y*b.y + a.z*b.z + a.w*b.w;
}

// ---- 1. partial sums over L for the sequence mean ----
__global__ __launch_bounds__(256) void kmean(const float4* __restrict__ h4,
                                             float4* __restrict__ part4) {
    const int c = blockIdx.x, b = blockIdx.y, t = threadIdx.x;
    const int LPER = SEQ / NCHUNK;  // 16
    const float4* p = h4 + ((size_t)b * SEQ + (size_t)c * LPER) * (DIM/4) + t;
    float4 a = make_float4(0.f, 0.f, 0.f, 0.f);
    #pragma unroll
    for (int i = 0; i < LPER; ++i) {
        float4 v = p[(size_t)i * (DIM/4)];
        a.x += v.x; a.y += v.y; a.z += v.z; a.w += v.w;
    }
    part4[((size_t)(b * NCHUNK + c)) * (DIM/4) + t] = a;
}

// ---- 2. reduce partials -> hbar -> logits -> softmax -> top2 (fused) ----
__global__ __launch_bounds__(256) void krouter(const float4* __restrict__ part4,
                                               const float4* __restrict__ rw4,
                                               float* __restrict__ out_logits,
                                               float* __restrict__ selw,
                                               int* __restrict__ sele) {
    const int b = blockIdx.x, t = threadIdx.x;
    const float4* p = part4 + (size_t)b * NCHUNK * (DIM/4) + t;
    float4 s = make_float4(0.f, 0.f, 0.f, 0.f);
    #pragma unroll 4
    for (int c = 0; c < NCHUNK; ++c) {
        float4 v = p[(size_t)c * (DIM/4)];
        s.x += v.x; s.y += v.y; s.z += v.z; s.w += v.w;
    }
    const float inv = 1.0f / (float)SEQ;
    s.x *= inv; s.y *= inv; s.z *= inv; s.w *= inv;

    __shared__ float red[4];
    __shared__ float lg[NE];
    const int wave = t >> 6, lane = t & 63;
    for (int e = 0; e < NE; ++e) {
        float4 w = rw4[(size_t)e * (DIM/4) + t];
        float pd = dot4(s, w);
        #pragma unroll
        for (int o = 32; o; o >>= 1) pd += __shfl_xor(pd, o);
        if (lane == 0) red[wave] = pd;
        __syncthreads();
        if (t == 0) {
            float l = red[0] + red[1] + red[2] + red[3];
            lg[e] = l;
            out_logits[b * NE + e] = l;
        }
        __syncthreads();
    }
    if (t == 0) {
        float l[NE];
        float mx = -1e30f;
        #pragma unroll
        for (int e = 0; e < NE; ++e) { l[e] = lg[e]; mx = fmaxf(mx, l[e]); }
        float sum = 0.f;
        #pragma unroll
        for (int e = 0; e < NE; ++e) { l[e] = expf(l[e] - mx); sum += l[e]; }
        const float invs = 1.f / sum;
        float v1 = -1.f, v2 = -1.f; int e1 = -1, e2 = -1;
        #pragma unroll
        for (int e = 0; e < NE; ++e) {
            float pe = l[e] * invs;
            if (pe > v1)      { v2 = v1; e2 = e1; v1 = pe; e1 = e; }
            else if (pe > v2) { v2 = pe; e2 = e; }
        }
        selw[b * 2 + 0] = v1; sele[b * 2 + 0] = e1;
        selw[b * 2 + 1] = v2; sele[b * 2 + 1] = e2;
    }
}

// ---- slot-list helper: bitmask + ffs, all compile-time-indexed ----
__device__ __forceinline__ int build_slots(const int* __restrict__ sele, int e, int* slot) {
    unsigned mask = 0;
    #pragma unroll
    for (int s = 0; s < NSLOT; ++s) mask |= (sele[s] == e) ? (1u << s) : 0u;
    const int m = __popc(mask);
    unsigned mm = mask;
    #pragma unroll
    for (int ti = 0; ti < MAXM; ++ti) { slot[ti] = __ffs(mm) - 1; mm &= mm - 1; }
    return m;
}

// ---- 3. up/gate + SiLU: 16-lane groups, 4 rows per wave in parallel ----
template<int M>
__device__ __forceinline__ void upgate_work(const float4* __restrict__ h4,
                                            const float4* __restrict__ w1_4,
                                            const float4* __restrict__ w3_4,
                                            float* __restrict__ act,
                                            const int* slot, int e, int tile, int t) {
    const int wave = t >> 6, g = (t >> 4) & 3, l = t & 15;
    const float4* xp[M];
    #pragma unroll
    for (int ti = 0; ti < M; ++ti) {
        const int s = slot[ti];
        xp[ti] = h4 + ((size_t)((s >> 1) * SEQ + (s & 1))) * (DIM/4) + l;
    }
    #pragma unroll
    for (int k = 0; k < 2; ++k) {
        const int row = tile * UG_TILE + wave * 8 + k * 4 + g;
        const float4* w1r = w1_4 + ((size_t)e * FF + row) * (DIM/4) + l;
        const float4* w3r = w3_4 + ((size_t)e * FF + row) * (DIM/4) + l;
        float up[M], gt[M];
        #pragma unroll
        for (int ti = 0; ti < M; ++ti) { up[ti] = 0.f; gt[ti] = 0.f; }
        #pragma unroll
        for (int it = 0; it < 16; ++it) {
            float4 a = w1r[it * 16];
            float4 c = w3r[it * 16];
            #pragma unroll
            for (int ti = 0; ti < M; ++ti) {
                float4 x = xp[ti][it * 16];
                up[ti] += dot4(a, x);
                gt[ti] += dot4(c, x);
            }
        }
        #pragma unroll
        for (int ti = 0; ti < M; ++ti) {
            float u = up[ti], gg = gt[ti];
            #pragma unroll
            for (int o = 8; o; o >>= 1) { u += __shfl_xor(u, o); gg += __shfl_xor(gg, o); }
            if (l == 0) {
                act[(size_t)slot[ti] * FF + row] = (u / (1.f + expf(-u))) * gg;
            }
        }
    }
}

__global__ __launch_bounds__(256) void kupgate(const float4* __restrict__ h4,
                                               const float4* __restrict__ w1_4,
                                               const float4* __restrict__ w3_4,
                                               const int* __restrict__ sele,
                                               float* __restrict__ act) {
    const int e = blockIdx.y, tile = blockIdx.x, t = threadIdx.x;
    int slot[MAXM];
    const int m = build_slots(sele, e, slot);
    if (m == 0) return;
    switch (m) {
        case 1: upgate_work<1>(h4, w1_4, w3_4, act, slot, e, tile, t); break;
        case 2: upgate_work<2>(h4, w1_4, w3_4, act, slot, e, tile, t); break;
        case 3: upgate_work<3>(h4, w1_4, w3_4, act, slot, e, tile, t); break;
        case 4: upgate_work<4>(h4, w1_4, w3_4, act, slot, e, tile, t); break;
        case 5: upgate_work<5>(h4, w1_4, w3_4, act, slot, e, tile, t); break;
        case 6: upgate_work<6>(h4, w1_4, w3_4, act, slot, e, tile, t); break;
        case 7: upgate_work<7>(h4, w1_4, w3_4, act, slot, e, tile, t); break;
        default: upgate_work<8>(h4, w1_4, w3_4, act, slot, e, tile, t); break;
    }
}

// ---- 4. down projection: same structure over FF=4096 ----
template<int M>
__device__ __forceinline__ void down_work(const float4* __restrict__ w2_4,
                                          const float4* __restrict__ act4,
                                          const float* __restrict__ selw,
                                          float* __restrict__ y,
                                          const int* slot, int e, int tile, int t) {
    const int wave = t >> 6, g = (t >> 4) & 3, l = t & 15;
    const float4* ap[M];
    float sw[M];
    #pragma unroll
    for (int ti = 0; ti < M; ++ti) {
        ap[ti] = act4 + (size_t)slot[ti] * (FF/4) + l;
        sw[ti] = selw[slot[ti]];
    }
    const int row = tile * DN_TILE + wave * 4 + g;
    const float4* w2r = w2_4 + ((size_t)e * DIM + row) * (FF/4) + l;
    float acc[M];
    #pragma unroll
    for (int ti = 0; ti < M; ++ti) acc[ti] = 0.f;
    #pragma unroll 16
    for (int it = 0; it < 64; ++it) {
        float4 w = w2r[it * 16];
        #pragma unroll
        for (int ti = 0; ti < M; ++ti) {
            acc[ti] += dot4(w, ap[ti][it * 16]);
        }
    }
    #pragma unroll
    for (int ti = 0; ti < M; ++ti) {
        float v = acc[ti];
        #pragma unroll
        for (int o = 8; o; o >>= 1) v += __shfl_xor(v, o);
        if (l == 0) y[(size_t)slot[ti] * DIM + row] = sw[ti] * v;
    }
}

__global__ __launch_bounds__(256) void kdown(const float4* __restrict__ w2_4,
                                             const float4* __restrict__ act4,
                                             const int* __restrict__ sele,
                                             const float* __restrict__ selw,
                                             float* __restrict__ y) {
    const int e = blockIdx.y, tile = blockIdx.x, t = threadIdx.x;
    int slot[MAXM];
    const int m = build_slots(sele, e, slot);
    if (m == 0) return;
    switch (m) {
        case 1: down_work<1>(w2_4, act4, selw, y, slot, e, tile, t); break;
        case 2: down_work<2>(w2_4, act4, selw, y, slot, e, tile, t); break;
        case 3: down_work<3>(w2_4, act4, selw, y, slot, e, tile, t); break;
        case 4: down_work<4>(w2_4, act4, selw, y, slot, e, tile, t); break;
        case 5: down_work<5>(w2_4, act4, selw, y, slot, e, tile, t); break;
        case 6: down_work<6>(w2_4, act4, selw, y, slot, e, tile, t); break;
        case 7: down_work<7>(w2_4, act4, selw, y, slot, e, tile, t); break;
        default: down_work<8>(w2_4, act4, selw, y, slot, e, tile, t); break;
    }
}

// ---- 5. combine two selections per batch, broadcast across L ----
__global__ __launch_bounds__(256) void kbcast(const float4* __restrict__ y4,
                                              float4* __restrict__ out4) {
    const int b = blockIdx.y, lg = blockIdx.x, t = threadIdx.x;
    float4 y0 = y4[(size_t)(2 * b) * (DIM/4) + t];
    float4 y1 = y4[(size_t)(2 * b + 1) * (DIM/4) + t];
    float4 c = make_float4(y0.x + y1.x, y0.y + y1.y, y0.z + y1.z, y0.w + y1.w);
    size_t base = ((size_t)b * SEQ + (size_t)lg * 8) * (DIM/4) + t;
    #pragma unroll
    for (int i = 0; i < 8; ++i) out4[base + (size_t)i * (DIM/4)] = c;
}

extern "C" void kernel_launch(void* const* d_in, const int* in_sizes, int n_in,
                              void* d_out, int out_size, void* d_ws, size_t ws_size,
                              hipStream_t stream) {
    const float* h  = (const float*)d_in[0];
    const float* rw = (const float*)d_in[1];
    const float* w1 = (const float*)d_in[2];
    const float* w2 = (const float*)d_in[3];
    const float* w3 = (const float*)d_in[4];
    float* out = (float*)d_out;
    float* ws  = (float*)d_ws;

    float* part   = ws + WS_PARTIAL;
    float* selw   = ws + WS_SELW;
    int*   sele   = (int*)(ws + WS_SELE);
    float* act    = ws + WS_ACT;
    float* y      = ws + WS_Y;
    float* out_logits = out + (size_t)BS * SEQ * DIM;

    kmean  <<<dim3(NCHUNK, BS), 256, 0, stream>>>((const float4*)h, (float4*)part);
    krouter<<<BS, 256, 0, stream>>>((const float4*)part, (const float4*)rw, out_logits, selw, sele);
    kupgate<<<dim3(FF / UG_TILE, NE), 256, 0, stream>>>((const float4*)h, (const float4*)w1,
                                                        (const float4*)w3, sele, act);
    kdown  <<<dim3(DIM / DN_TILE, NE), 256, 0, stream>>>((const float4*)w2, (const float4*)act,
                                                         sele, selw, y);
    kbcast <<<dim3(SEQ / 8, BS), 256, 0, stream>>>((const float4*)y, (float4*)out);
}